// Round 2
// baseline (386.530 us; speedup 1.0000x reference)
//
#include <hip/hip_runtime.h>

#define BIGV 1e10f

constexpr int BN = 64;     // batches
constexpr int NN = 512;    // rows (x)
constexpr int MM = 512;    // cols (y)
constexpr int DD = 16;     // feature dim
constexpr float INV_LN2 = 1.4426950408889634f;
constexpr float LN2f    = 0.6931471805599453f;

// One block per batch; thread t owns row i = t+1. Anti-diagonal wavefront DP
// with 3 rotating r-buffers in LDS. Softmin done in log2 domain (inputs
// pre-scaled by 1/ln2) so we use native v_exp_f32 / v_log_f32 directly.
__global__ __launch_bounds__(512, 1) void sdtw_kernel(
    const float* __restrict__ X, const float* __restrict__ Y,
    float* __restrict__ out)
{
  const int b = blockIdx.x;
  const int t = threadIdx.x;              // row i = t+1 (1-based)

  __shared__ float rbuf[3][520];          // r over ii = 0..512 (513 used)
  __shared__ float y2sh[MM];              // |y_j|^2 / ln2

  const float* xrow  = X + ((size_t)b * NN + t) * DD;
  const float* ybase = Y + (size_t)b * MM * DD;

  // x_i into registers, pre-scaled by 1/ln2 (so dot gives x.y/ln2)
  float xi[DD];
  float x2 = 0.f;
  #pragma unroll
  for (int q = 0; q < DD; ++q) { float v = xrow[q]; xi[q] = v * INV_LN2; x2 = fmaf(v, v, x2); }
  x2 *= INV_LN2;

  // |y_t|^2 / ln2 into LDS
  {
    const float* yr = ybase + (size_t)t * DD;
    float s = 0.f;
    #pragma unroll
    for (int q = 0; q < DD; ++q) { float v = yr[q]; s = fmaf(v, v, s); }
    y2sh[t] = s * INV_LN2;
  }

  // init: buffer0 = diag k=0 (only (0,0)=0), buffer1 = diag k=1 (all BIG)
  rbuf[0][t + 1] = BIGV;
  rbuf[1][t + 1] = BIGV;
  if (t == 0) { rbuf[0][0] = 0.f; rbuf[1][0] = BIGV; rbuf[2][0] = BIGV; }

  // first y row for k=2: yrow = -t (clamped; only t=0 is valid)
  float4 c0, c1, c2, c3;
  {
    int yc = -t; yc = yc < 0 ? 0 : yc;
    const float4* yr = (const float4*)(ybase + (size_t)yc * DD);
    c0 = yr[0]; c1 = yr[1]; c2 = yr[2]; c3 = yr[3];
  }

  __syncthreads();

  int ia = 0, ib = 1, ic = 2;   // ia = diag k-2, ib = diag k-1, ic = write (diag k)
  float last = 0.f;

  for (int k = 2; k <= NN + MM; ++k) {
    const int yrow = k - t - 2;            // 0-based y row (= j-1)

    // rolling prefetch of next step's y row (always in-bounds via clamp)
    float4 n0, n1, n2, n3;
    {
      int yn = yrow + 1; yn = yn < 0 ? 0 : (yn > MM - 1 ? MM - 1 : yn);
      const float4* yr = (const float4*)(ybase + (size_t)yn * DD);
      n0 = yr[0]; n1 = yr[1]; n2 = yr[2]; n3 = yr[3];
    }

    const int ycl = yrow < 0 ? 0 : (yrow > MM - 1 ? MM - 1 : yrow);
    const float y2v = y2sh[ycl];

    // d' = (x2 + y2 - 2 x.y)/ln2   (scales pre-folded)
    float s0 = xi[0]  * c0.x, s1 = xi[1]  * c0.y, s2 = xi[2]  * c0.z, s3 = xi[3]  * c0.w;
    s0 = fmaf(xi[4],  c1.x, s0); s1 = fmaf(xi[5],  c1.y, s1);
    s2 = fmaf(xi[6],  c1.z, s2); s3 = fmaf(xi[7],  c1.w, s3);
    s0 = fmaf(xi[8],  c2.x, s0); s1 = fmaf(xi[9],  c2.y, s1);
    s2 = fmaf(xi[10], c2.z, s2); s3 = fmaf(xi[11], c2.w, s3);
    s0 = fmaf(xi[12], c3.x, s0); s1 = fmaf(xi[13], c3.y, s1);
    s2 = fmaf(xi[14], c3.z, s2); s3 = fmaf(xi[15], c3.w, s3);
    const float dot  = (s0 + s1) + (s2 + s3);
    const float dval = x2 + y2v - 2.f * dot;

    // softmin of (diag, up, left) in log2 domain
    const float a  = rbuf[ia][t];          // r_{k-2}[ii-1]  (i-1, j-1)
    const float bu = rbuf[ib][t];          // r_{k-1}[ii-1]  (i-1, j)
    const float bl = rbuf[ib][t + 1];      // r_{k-1}[ii]    (i, j-1)
    const float mn = fminf(fminf(a, bu), bl);
    const float e  = __builtin_amdgcn_exp2f(mn - a)
                   + __builtin_amdgcn_exp2f(mn - bu)
                   + __builtin_amdgcn_exp2f(mn - bl);
    const float smin = mn - __builtin_amdgcn_logf(e);

    const bool valid = (yrow >= 0) & (yrow < MM);
    const float rnew = valid ? (dval + smin) : BIGV;

    rbuf[ic][t + 1] = rnew;
    if (t == 0) rbuf[ic][0] = BIGV;        // slot 0 must be BIG for diags >= 1

    __syncthreads();

    const int tmp = ia; ia = ib; ib = ic; ic = tmp;
    c0 = n0; c1 = n1; c2 = n2; c3 = n3;
    if (k == NN + MM) last = rnew;
  }

  // final diagonal's entry ii = N, computed by thread N-1, times ln2
  if (t == NN - 1) out[b] = last * LN2f;
}

extern "C" void kernel_launch(void* const* d_in, const int* in_sizes, int n_in,
                              void* d_out, int out_size, void* d_ws, size_t ws_size,
                              hipStream_t stream)
{
  const float* x = (const float*)d_in[0];
  const float* y = (const float*)d_in[1];
  float* o = (float*)d_out;
  sdtw_kernel<<<BN, 512, 0, stream>>>(x, y, o);
}

// Round 3
// 318.116 us; speedup vs baseline: 1.2151x; 1.2151x over previous
//
#include <hip/hip_runtime.h>

#define BIGV 1e10f

constexpr float INV_LN2 = 1.4426950408889634f;
constexpr float LN2f    = 0.6931471805599453f;

__device__ __forceinline__ float softmin3(float da, float db, float dc) {
  float mn = fminf(fminf(da, db), dc);
  float e = __builtin_amdgcn_exp2f(mn - da)
          + __builtin_amdgcn_exp2f(mn - db)
          + __builtin_amdgcn_exp2f(mn - dc);
  return mn - __builtin_amdgcn_logf(e);
}

// One block (256 threads = 4 waves) per batch. Wave w owns rows w*128+1..w*128+128
// (1-based DP rows), 2 rows per lane. DP state in registers; cross-lane via
// __shfl_up; cross-wave via a tiny parity-double-buffered LDS slot (1 barrier/step).
// y is LDS-resident (parity-split, 5-float4-padded rows: stride-2-row reads are
// ~2-way = conflict-free). No global memory ops inside the k-loop.
__global__ __launch_bounds__(256, 1) void sdtw_kernel(
    const float* __restrict__ X, const float* __restrict__ Y,
    float* __restrict__ out)
{
  const int b    = blockIdx.x;
  const int tid  = threadIdx.x;
  const int w    = tid >> 6;
  const int lane = tid & 63;

  __shared__ float4 yE[256][5];   // even y rows, padded to 80B (16B-aligned)
  __shared__ float4 yO[256][5];   // odd  y rows
  __shared__ float  y2sh[512];    // |y_j|^2 / ln2
  __shared__ float  bnd[2][8];    // per-parity wave-boundary r values

  const float* xb = X + (size_t)b * 512 * 16;
  const float* yb = Y + (size_t)b * 512 * 16;

  // ---- stage Y into LDS (row-parity split) + y2 ----
  for (int r = tid; r < 512; r += 256) {
    const float4* src = (const float4*)(yb + r * 16);
    float4 v0 = src[0], v1 = src[1], v2 = src[2], v3 = src[3];
    float4* dst = (r & 1) ? yO[r >> 1] : yE[r >> 1];
    dst[0] = v0; dst[1] = v1; dst[2] = v2; dst[3] = v3;
    float s = 0.f;
    s = fmaf(v0.x, v0.x, s); s = fmaf(v0.y, v0.y, s);
    s = fmaf(v0.z, v0.z, s); s = fmaf(v0.w, v0.w, s);
    s = fmaf(v1.x, v1.x, s); s = fmaf(v1.y, v1.y, s);
    s = fmaf(v1.z, v1.z, s); s = fmaf(v1.w, v1.w, s);
    s = fmaf(v2.x, v2.x, s); s = fmaf(v2.y, v2.y, s);
    s = fmaf(v2.z, v2.z, s); s = fmaf(v2.w, v2.w, s);
    s = fmaf(v3.x, v3.x, s); s = fmaf(v3.y, v3.y, s);
    s = fmaf(v3.z, v3.z, s); s = fmaf(v3.w, v3.w, s);
    y2sh[r] = s * INV_LN2;
  }
  if (tid < 16) bnd[tid >> 3][tid & 7] = BIGV;

  // ---- x rows (2 per lane, contiguous 128B) ----
  const int i0 = w * 128 + 2 * lane;    // 0-based x row of cell0; cell1 = i0+1
  float xA[16], xB[16];
  float x2A = 0.f, x2B = 0.f;
  {
    const float4* sa = (const float4*)(xb + (size_t)i0 * 16);
    float4 u0 = sa[0], u1 = sa[1], u2 = sa[2], u3 = sa[3];
    float4 u4 = sa[4], u5 = sa[5], u6 = sa[6], u7 = sa[7];
    float ta[16] = { u0.x,u0.y,u0.z,u0.w, u1.x,u1.y,u1.z,u1.w,
                     u2.x,u2.y,u2.z,u2.w, u3.x,u3.y,u3.z,u3.w };
    float tb[16] = { u4.x,u4.y,u4.z,u4.w, u5.x,u5.y,u5.z,u5.w,
                     u6.x,u6.y,u6.z,u6.w, u7.x,u7.y,u7.z,u7.w };
    #pragma unroll
    for (int q = 0; q < 16; ++q) {
      x2A = fmaf(ta[q], ta[q], x2A); xA[q] = ta[q] * INV_LN2;
      x2B = fmaf(tb[q], tb[q], x2B); xB[q] = tb[q] * INV_LN2;
    }
    x2A *= INV_LN2; x2B *= INV_LN2;
  }

  // DP registers: a* = diag k-1, b* = diag k-2 entering each step.
  float a0 = BIGV, a1 = BIGV, b0 = BIGV, b1 = BIGV;
  float prevB = (tid == 0) ? 0.f : BIGV;   // r_{k-2}[w*128] for lane 0
  const int s1 = i0 + 2;                   // u0 = k - s1 (= jj0-1, unclamped)

  __syncthreads();

  // rolling y regs: Ya holds row (t0(k)-1) entering step k
  float Y0r[16], Y1r[16];
  float y20, y21;
  {
    const float4* p = (const float4*)yE[0];   // garbage row, masked at k=2
    float4 f0 = p[0], f1 = p[1], f2 = p[2], f3 = p[3];
    Y0r[0]=f0.x; Y0r[1]=f0.y; Y0r[2]=f0.z; Y0r[3]=f0.w;
    Y0r[4]=f1.x; Y0r[5]=f1.y; Y0r[6]=f1.z; Y0r[7]=f1.w;
    Y0r[8]=f2.x; Y0r[9]=f2.y; Y0r[10]=f2.z; Y0r[11]=f2.w;
    Y0r[12]=f3.x; Y0r[13]=f3.y; Y0r[14]=f3.z; Y0r[15]=f3.w;
    y20 = y2sh[0];
    #pragma unroll
    for (int q = 0; q < 16; ++q) Y1r[q] = 0.f;
    y21 = 0.f;
  }

  auto stepf = [&](int k, int par,
                   float& A0, float& A1, float& B0, float& B1,
                   float (&Ya)[16], float (&Yb)[16],
                   float& y2a, float& y2b) {
    const int u0 = k - s1;
    int tc = u0 < 0 ? 0 : (u0 > 511 ? 511 : u0);
    const bool v0 = (unsigned)u0 <= 511u;
    const bool v1 = (unsigned)(u0 - 1) <= 511u;

    // fresh y row -> Yb (parity of valid row == k&1)
    const float4* yp_ = par ? (const float4*)yO[tc >> 1]
                            : (const float4*)yE[tc >> 1];
    float4 f0 = yp_[0], f1 = yp_[1], f2 = yp_[2], f3 = yp_[3];
    y2b = y2sh[tc];
    const float br  = bnd[par ^ 1][w];     // r_{k-1}[w*128]
    const float shA = __shfl_up(A1, 1);
    const float shB = __shfl_up(B1, 1);

    // cell1 first (row ii1=i0+2): only own-register deps -> hides LDS latency
    float p0 = 0.f, p1 = 0.f, p2 = 0.f, p3 = 0.f;
    #pragma unroll
    for (int q = 0; q < 16; q += 4) {
      p0 = fmaf(xB[q],     Ya[q],     p0);
      p1 = fmaf(xB[q + 1], Ya[q + 1], p1);
      p2 = fmaf(xB[q + 2], Ya[q + 2], p2);
      p3 = fmaf(xB[q + 3], Ya[q + 3], p3);
    }
    const float d1 = x2B + y2a - 2.f * ((p0 + p1) + (p2 + p3));
    const float n1 = v1 ? d1 + softmin3(B0, A0, A1) : BIGV;

    Yb[0]=f0.x; Yb[1]=f0.y; Yb[2]=f0.z; Yb[3]=f0.w;
    Yb[4]=f1.x; Yb[5]=f1.y; Yb[6]=f1.z; Yb[7]=f1.w;
    Yb[8]=f2.x; Yb[9]=f2.y; Yb[10]=f2.z; Yb[11]=f2.w;
    Yb[12]=f3.x; Yb[13]=f3.y; Yb[14]=f3.z; Yb[15]=f3.w;

    // cell0 (row ii0=i0+1): neighbors from shfl / boundary
    const float dg = (lane == 0) ? prevB : shB;   // r_{k-2}[ii0-1]
    const float up = (lane == 0) ? br   : shA;    // r_{k-1}[ii0-1]
    prevB = br;
    float q0 = 0.f, q1 = 0.f, q2 = 0.f, q3 = 0.f;
    #pragma unroll
    for (int q = 0; q < 16; q += 4) {
      q0 = fmaf(xA[q],     Yb[q],     q0);
      q1 = fmaf(xA[q + 1], Yb[q + 1], q1);
      q2 = fmaf(xA[q + 2], Yb[q + 2], q2);
      q3 = fmaf(xA[q + 3], Yb[q + 3], q3);
    }
    const float d0 = x2A + y2b - 2.f * ((q0 + q1) + (q2 + q3));
    const float n0 = v0 ? d0 + softmin3(dg, up, A0) : BIGV;

    if (lane == 63) bnd[par][w + 1] = n1;   // publish r_k[w*128+128]
    B0 = n0; B1 = n1;                       // new diag k replaces k-2
    __syncthreads();
  };

  int k = 2;
  for (int p = 0; p < 511; ++p) {
    stepf(k,     0, a0, a1, b0, b1, Y0r, Y1r, y20, y21);
    stepf(k + 1, 1, b0, b1, a0, a1, Y1r, Y0r, y21, y20);
    k += 2;
  }
  stepf(1024, 0, a0, a1, b0, b1, Y0r, Y1r, y20, y21);

  // r_{1024}[512] lives in b1 of wave 3, lane 63
  if (tid == 255) out[b] = b1 * LN2f;
}

extern "C" void kernel_launch(void* const* d_in, const int* in_sizes, int n_in,
                              void* d_out, int out_size, void* d_ws, size_t ws_size,
                              hipStream_t stream)
{
  const float* x = (const float*)d_in[0];
  const float* y = (const float*)d_in[1];
  float* o = (float*)d_out;
  sdtw_kernel<<<64, 256, 0, stream>>>(x, y, o);
}

// Round 5
// 172.774 us; speedup vs baseline: 2.2372x; 1.8412x over previous
//
#include <hip/hip_runtime.h>

#define BIGV 1e10f

constexpr float INV_LN2 = 1.4426950408889634f;
constexpr float LN2f    = 0.6931471805599453f;

// ---------------- Phase 1: ND[b][j][i] = -(|x_i - y_j|^2)/ln2 as f16 ----------------
__global__ __launch_bounds__(256) void dist_kernel(
    const float* __restrict__ X, const float* __restrict__ Y,
    _Float16* __restrict__ ND)
{
  const int b  = blockIdx.x;
  const int j0 = blockIdx.y * 8;
  const int t  = threadIdx.x;

  __shared__ float4 ysh4[8][4];
  __shared__ float  y2sh[8];
  float* yshf = (float*)ysh4;

  const float* xb = X + (size_t)b * 512 * 16;
  const float* yb = Y + (size_t)b * 512 * 16;

  if (t < 128) yshf[t] = yb[(size_t)(j0 + (t >> 4)) * 16 + (t & 15)];
  __syncthreads();
  if (t < 8) {
    float s = 0.f;
    #pragma unroll
    for (int q = 0; q < 16; ++q) s = fmaf(yshf[t * 16 + q], yshf[t * 16 + q], s);
    y2sh[t] = s;
  }
  __syncthreads();

  float xa[16], xc[16];
  float x2a = 0.f, x2c = 0.f;
  {
    const float4* pa = (const float4*)(xb + (size_t)(2 * t) * 16);
    float4 A0 = pa[0], A1 = pa[1], A2 = pa[2], A3 = pa[3];
    float4 B0 = pa[4], B1 = pa[5], B2 = pa[6], B3 = pa[7];
    float ta[16] = { A0.x,A0.y,A0.z,A0.w, A1.x,A1.y,A1.z,A1.w,
                     A2.x,A2.y,A2.z,A2.w, A3.x,A3.y,A3.z,A3.w };
    float tb[16] = { B0.x,B0.y,B0.z,B0.w, B1.x,B1.y,B1.z,B1.w,
                     B2.x,B2.y,B2.z,B2.w, B3.x,B3.y,B3.z,B3.w };
    #pragma unroll
    for (int q = 0; q < 16; ++q) {
      xa[q] = ta[q]; x2a = fmaf(ta[q], ta[q], x2a);
      xc[q] = tb[q]; x2c = fmaf(tb[q], tb[q], x2c);
    }
  }

  unsigned int* outp = (unsigned int*)(ND + ((size_t)b * 512 + j0) * 512);
  #pragma unroll
  for (int jj = 0; jj < 8; ++jj) {
    float4 y0 = ysh4[jj][0], y1 = ysh4[jj][1], y2v = ysh4[jj][2], y3 = ysh4[jj][3];
    float yv[16] = { y0.x,y0.y,y0.z,y0.w, y1.x,y1.y,y1.z,y1.w,
                     y2v.x,y2v.y,y2v.z,y2v.w, y3.x,y3.y,y3.z,y3.w };
    float da = 0.f, dc = 0.f;
    #pragma unroll
    for (int q = 0; q < 16; ++q) {
      da = fmaf(xa[q], yv[q], da);
      dc = fmaf(xc[q], yv[q], dc);
    }
    const float nda = (2.f * da - x2a - y2sh[jj]) * INV_LN2;   // = -d'/1
    const float ndc = (2.f * dc - x2c - y2sh[jj]) * INV_LN2;
    const unsigned short lo = __builtin_bit_cast(unsigned short, (_Float16)nda);
    const unsigned short hi = __builtin_bit_cast(unsigned short, (_Float16)ndc);
    outp[(size_t)jj * 256 + t] = ((unsigned int)hi << 16) | lo;
  }
}

// ---------------- Phase 2: log2-domain wavefront DP, phased 4-wave pipeline ----------------
// Block = 256 thr = 4 waves; wave w owns DP rows 128w+1..128w+128; lane l owns
// rows a+1, a+2 (a = 128w + 2l). Step t: lane l at column j = t - l.
// Cross-lane: shfl_up of lane (l-1)'s cell1 from t-1 (up) and t-2 (diag).
// Cross-wave: LDS ring[3][64] of boundary rows 128/256/384, lag 5 phases, K=16.
template<bool PRE>
__global__ __launch_bounds__(256, 1) void dp_kernel(
    const _Float16* __restrict__ ND, const float* __restrict__ X,
    const float* __restrict__ Y, float* __restrict__ out)
{
  const int b   = blockIdx.x;
  const int tid = threadIdx.x;
  const int w   = tid >> 6;
  const int l   = tid & 63;
  const int a   = 128 * w + 2 * l;        // x-row of cell0; DP rows a+1, a+2

  __shared__ float ring[3][64];
  if (tid < 3) ring[tid][0] = BIGV;

  const _Float16* nb = ND + (size_t)b * 512 * 512;

  float n0p = BIGV, n1p1 = BIGV, n1p2 = BIGV, lastv = BIGV;

  unsigned ds0 = 0, ds1 = 0, ds2 = 0, ds3 = 0;      // PRE prefetch slots
  float xr0[16], xr1[16], yc[16], yn[16];           // !PRE
  float x20 = 0.f, x21 = 0.f;

  if constexpr (PRE) {
    #pragma unroll
    for (int s = 0; s < 4; ++s) {
      int jc = s - l; jc = jc < 0 ? 0 : jc;         // step t=s+1: col j-1 = t-1-l
      unsigned v = *(const unsigned*)(nb + ((size_t)jc << 9) + a);
      if (s == 0) ds0 = v; else if (s == 1) ds1 = v;
      else if (s == 2) ds2 = v; else ds3 = v;
    }
  } else {
    const float* xb = X + (size_t)b * 512 * 16;
    const float* yb = Y + (size_t)b * 512 * 16;
    const float4* px = (const float4*)(xb + (size_t)a * 16);
    float4 u0 = px[0], u1 = px[1], u2 = px[2], u3 = px[3];
    float4 u4 = px[4], u5 = px[5], u6 = px[6], u7 = px[7];
    float ta[16] = { u0.x,u0.y,u0.z,u0.w, u1.x,u1.y,u1.z,u1.w,
                     u2.x,u2.y,u2.z,u2.w, u3.x,u3.y,u3.z,u3.w };
    float tb[16] = { u4.x,u4.y,u4.z,u4.w, u5.x,u5.y,u5.z,u5.w,
                     u6.x,u6.y,u6.z,u6.w, u7.x,u7.y,u7.z,u7.w };
    #pragma unroll
    for (int q = 0; q < 16; ++q) {
      xr0[q] = ta[q]; x20 = fmaf(ta[q], ta[q], x20);
      xr1[q] = tb[q]; x21 = fmaf(tb[q], tb[q], x21);
    }
    const float4* py = (const float4*)(yb + (size_t)0 * 16);  // col for t=1: clamp(-l)=0
    float4 v0 = py[0], v1 = py[1], v2 = py[2], v3 = py[3];
    float tv[16] = { v0.x,v0.y,v0.z,v0.w, v1.x,v1.y,v1.z,v1.w,
                     v2.x,v2.y,v2.z,v2.w, v3.x,v3.y,v3.z,v3.w };
    #pragma unroll
    for (int q = 0; q < 16; ++q) yc[q] = tv[q];
  }

  const float* ybase = Y + (size_t)b * 512 * 16;   // !PRE in-loop y loads

#define SDTW_STEP(DSLOT)                                                       \
  {                                                                            \
    const int j = t - l;                                                       \
    float nd0, nd1;                                                            \
    if constexpr (PRE) {                                                       \
      const unsigned dw = DSLOT;                                               \
      int jn = t + 3 - l; jn = jn < 0 ? 0 : (jn > 511 ? 511 : jn);             \
      DSLOT = *(const unsigned*)(nb + ((size_t)jn << 9) + a);                  \
      const _Float16 h0 = __builtin_bit_cast(_Float16, (unsigned short)(dw & 0xffffu)); \
      const _Float16 h1 = __builtin_bit_cast(_Float16, (unsigned short)(dw >> 16));     \
      nd0 = (float)h0; nd1 = (float)h1;                                        \
    } else {                                                                   \
      int jn = t - l; jn = jn < 0 ? 0 : (jn > 511 ? 511 : jn);                 \
      const float4* py = (const float4*)(ybase + (size_t)jn * 16);             \
      float4 v0 = py[0], v1 = py[1], v2 = py[2], v3 = py[3];                   \
      yn[0]=v0.x; yn[1]=v0.y; yn[2]=v0.z; yn[3]=v0.w;                          \
      yn[4]=v1.x; yn[5]=v1.y; yn[6]=v1.z; yn[7]=v1.w;                          \
      yn[8]=v2.x; yn[9]=v2.y; yn[10]=v2.z; yn[11]=v2.w;                        \
      yn[12]=v3.x; yn[13]=v3.y; yn[14]=v3.z; yn[15]=v3.w;                      \
      float y2 = 0.f, d0 = 0.f, d1 = 0.f;                                      \
      _Pragma("unroll")                                                        \
      for (int q = 0; q < 16; ++q) {                                           \
        y2 = fmaf(yc[q], yc[q], y2);                                           \
        d0 = fmaf(xr0[q], yc[q], d0);                                          \
        d1 = fmaf(xr1[q], yc[q], d1);                                          \
      }                                                                        \
      nd0 = (2.f * d0 - x20 - y2) * INV_LN2;                                   \
      nd1 = (2.f * d1 - x21 - y2) * INV_LN2;                                   \
    }                                                                          \
    float up_sh = __shfl_up(n1p1, 1);                                          \
    float dg_sh = __shfl_up(n1p2, 1);                                          \
    if (l == 0) {                                                              \
      if (w == 0) { up_sh = BIGV; dg_sh = (j == 1) ? 0.f : BIGV; }             \
      else { up_sh = ring[w - 1][j & 63]; dg_sh = ring[w - 1][(j - 1) & 63]; } \
    }                                                                          \
    /* cell0: DP row a+1 */                                                    \
    const float mn0 = fminf(fminf(dg_sh, up_sh), n0p);                         \
    const float s0 = __builtin_amdgcn_exp2f(mn0 - dg_sh)                       \
                   + __builtin_amdgcn_exp2f(mn0 - up_sh)                       \
                   + __builtin_amdgcn_exp2f(mn0 - n0p);                        \
    float c0 = mn0 - __builtin_amdgcn_logf(s0) - nd0;                          \
    /* cell1: DP row a+2: diag=n0p(old), left=n1p1(old), up=c0 */              \
    const float mn1 = fminf(fminf(n0p, n1p1), c0);                             \
    const float s1 = __builtin_amdgcn_exp2f(mn1 - n0p)                         \
                   + __builtin_amdgcn_exp2f(mn1 - n1p1)                        \
                   + __builtin_amdgcn_exp2f(mn1 - c0);                         \
    float c1 = mn1 - __builtin_amdgcn_logf(s1) - nd1;                          \
    const bool valid = (unsigned)(j - 1) < 512u;                               \
    c0 = valid ? c0 : BIGV;                                                    \
    c1 = valid ? c1 : BIGV;                                                    \
    if (valid) lastv = c1;                                                     \
    n1p2 = n1p1; n1p1 = c1; n0p = c0;                                          \
    if (l == 63 && w < 3 && valid) ring[w][j & 63] = c1;                       \
    if constexpr (!PRE) {                                                      \
      _Pragma("unroll")                                                        \
      for (int q = 0; q < 16; ++q) yc[q] = yn[q];                              \
    }                                                                          \
  }

  for (int p = 0; p < 51; ++p) {
    const int pw = p - 5 * w;
    if (pw >= 0 && pw <= 35) {
      const int tbase = 16 * pw + 1;
      #pragma unroll
      for (int g = 0; g < 4; ++g) {
        { const int t = tbase + 4 * g;     SDTW_STEP(ds0) }
        { const int t = tbase + 4 * g + 1; SDTW_STEP(ds1) }
        { const int t = tbase + 4 * g + 2; SDTW_STEP(ds2) }
        { const int t = tbase + 4 * g + 3; SDTW_STEP(ds3) }
      }
    }
    __syncthreads();
  }
#undef SDTW_STEP

  // wave 3, lane 63: last valid c1 was t=575 -> r(512,512) in log2 units
  if (tid == 255) out[b] = lastv * LN2f;
}

extern "C" void kernel_launch(void* const* d_in, const int* in_sizes, int n_in,
                              void* d_out, int out_size, void* d_ws, size_t ws_size,
                              hipStream_t stream)
{
  const float* x = (const float*)d_in[0];
  const float* y = (const float*)d_in[1];
  float* o = (float*)d_out;
  const size_t need = (size_t)64 * 512 * 512 * 2;
  if (ws_size >= need) {
    _Float16* nd = (_Float16*)d_ws;
    dist_kernel<<<dim3(64, 64), 256, 0, stream>>>(x, y, nd);
    dp_kernel<true><<<64, 256, 0, stream>>>(nd, x, y, o);
  } else {
    dp_kernel<false><<<64, 256, 0, stream>>>(nullptr, x, y, o);
  }
}

// Round 7
// 147.626 us; speedup vs baseline: 2.6183x; 1.1703x over previous
//
#include <hip/hip_runtime.h>

#define BIGV 1e10f

constexpr float INV_LN2 = 1.4426950408889634f;
constexpr float LN2f    = 0.6931471805599453f;

// ---------------- Phase 1: ND[b][j][i] = -(|x_i - y_j|^2)/ln2 as f16 ----------------
__global__ __launch_bounds__(256) void dist_kernel(
    const float* __restrict__ X, const float* __restrict__ Y,
    _Float16* __restrict__ ND)
{
  const int b  = blockIdx.x;
  const int j0 = blockIdx.y * 8;
  const int t  = threadIdx.x;

  __shared__ float4 ysh4[8][4];
  __shared__ float  y2sh[8];
  float* yshf = (float*)ysh4;

  const float* xb = X + (size_t)b * 512 * 16;
  const float* yb = Y + (size_t)b * 512 * 16;

  if (t < 128) yshf[t] = yb[(size_t)(j0 + (t >> 4)) * 16 + (t & 15)];
  __syncthreads();
  if (t < 8) {
    float s = 0.f;
    #pragma unroll
    for (int q = 0; q < 16; ++q) s = fmaf(yshf[t * 16 + q], yshf[t * 16 + q], s);
    y2sh[t] = s;
  }
  __syncthreads();

  float xa[16], xc[16];
  float x2a = 0.f, x2c = 0.f;
  {
    const float4* pa = (const float4*)(xb + (size_t)(2 * t) * 16);
    float4 A0 = pa[0], A1 = pa[1], A2 = pa[2], A3 = pa[3];
    float4 B0 = pa[4], B1 = pa[5], B2 = pa[6], B3 = pa[7];
    float ta[16] = { A0.x,A0.y,A0.z,A0.w, A1.x,A1.y,A1.z,A1.w,
                     A2.x,A2.y,A2.z,A2.w, A3.x,A3.y,A3.z,A3.w };
    float tb[16] = { B0.x,B0.y,B0.z,B0.w, B1.x,B1.y,B1.z,B1.w,
                     B2.x,B2.y,B2.z,B2.w, B3.x,B3.y,B3.z,B3.w };
    #pragma unroll
    for (int q = 0; q < 16; ++q) {
      xa[q] = ta[q]; x2a = fmaf(ta[q], ta[q], x2a);
      xc[q] = tb[q]; x2c = fmaf(tb[q], tb[q], x2c);
    }
  }

  unsigned int* outp = (unsigned int*)(ND + ((size_t)b * 512 + j0) * 512);
  #pragma unroll
  for (int jj = 0; jj < 8; ++jj) {
    float4 y0 = ysh4[jj][0], y1 = ysh4[jj][1], y2v = ysh4[jj][2], y3 = ysh4[jj][3];
    float yv[16] = { y0.x,y0.y,y0.z,y0.w, y1.x,y1.y,y1.z,y1.w,
                     y2v.x,y2v.y,y2v.z,y2v.w, y3.x,y3.y,y3.z,y3.w };
    float da = 0.f, dc = 0.f;
    #pragma unroll
    for (int q = 0; q < 16; ++q) {
      da = fmaf(xa[q], yv[q], da);
      dc = fmaf(xc[q], yv[q], dc);
    }
    const float nda = (2.f * da - x2a - y2sh[jj]) * INV_LN2;
    const float ndc = (2.f * dc - x2c - y2sh[jj]) * INV_LN2;
    const unsigned short lo = __builtin_bit_cast(unsigned short, (_Float16)nda);
    const unsigned short hi = __builtin_bit_cast(unsigned short, (_Float16)ndc);
    outp[(size_t)jj * 256 + t] = ((unsigned int)hi << 16) | lo;
  }
}

// ---------------- Phase 2: log2-domain wavefront DP, phased 4-wave pipeline ----------------
// Wave w owns DP rows 128w+1..128w+128; lane l owns rows a+1,a+2 (a=128w+2l).
// Step t: lane l at col j=t-l. Cross-lane shift via single DPP wf_sr1 (0x138);
// dg = previous step's up. Cross-wave: ring[3][64] in LDS, LAG 5 phases of 16
// steps (producer lane63 trails its lane0 by 63 cols ~ 4 phases -> lag >= 5);
// lane-0 boundary values prefetched per phase as 4 aligned ds_read_b128.
template<bool PRE>
__global__ __launch_bounds__(256, 1) void dp_kernel(
    const _Float16* __restrict__ ND, const float* __restrict__ X,
    const float* __restrict__ Y, float* __restrict__ out)
{
  const int b   = blockIdx.x;
  const int tid = threadIdx.x;
  const int w   = tid >> 6;
  const int l   = tid & 63;
  const int a   = 128 * w + 2 * l;

  __shared__ float ring[3][64];

  const _Float16* nb    = ND + (size_t)b * 512 * 512;
  const float*    ybase = Y + (size_t)b * 512 * 16;

  float n0p = BIGV, n1p1 = BIGV, lastv = BIGV;
  float upprev = (w == 0 && l == 0) ? 0.f : BIGV;   // dg for first step

  unsigned ds0 = 0, ds1 = 0, ds2 = 0, ds3 = 0;
  float xr0[16], xr1[16];
  float x20 = 0.f, x21 = 0.f;

  if constexpr (PRE) {
    #pragma unroll
    for (int s = 0; s < 4; ++s) {
      int jc = s - l; jc = jc < 0 ? 0 : jc;
      unsigned v = *(const unsigned*)(nb + ((size_t)jc << 9) + a);
      if (s == 0) ds0 = v; else if (s == 1) ds1 = v;
      else if (s == 2) ds2 = v; else ds3 = v;
    }
  } else {
    const float4* px = (const float4*)(X + ((size_t)b * 512 + a) * 16);
    float4 u0 = px[0], u1 = px[1], u2 = px[2], u3 = px[3];
    float4 u4 = px[4], u5 = px[5], u6 = px[6], u7 = px[7];
    float ta[16] = { u0.x,u0.y,u0.z,u0.w, u1.x,u1.y,u1.z,u1.w,
                     u2.x,u2.y,u2.z,u2.w, u3.x,u3.y,u3.z,u3.w };
    float tb[16] = { u4.x,u4.y,u4.z,u4.w, u5.x,u5.y,u5.z,u5.w,
                     u6.x,u6.y,u6.z,u6.w, u7.x,u7.y,u7.z,u7.w };
    #pragma unroll
    for (int q = 0; q < 16; ++q) {
      xr0[q] = ta[q]; x20 = fmaf(ta[q], ta[q], x20);
      xr1[q] = tb[q]; x21 = fmaf(tb[q], tb[q], x21);
    }
  }
  __syncthreads();

#define SDTW_STEP(DSLOT, RINGV)                                                \
  {                                                                            \
    const int j = t - l;                                                       \
    float nd0, nd1;                                                            \
    if constexpr (PRE) {                                                       \
      const unsigned dw = DSLOT;                                               \
      int jn = t + 3 - l; jn = jn < 0 ? 0 : (jn > 511 ? 511 : jn);             \
      DSLOT = *(const unsigned*)(nb + ((size_t)jn << 9) + a);                  \
      nd0 = (float)__builtin_bit_cast(_Float16, (unsigned short)(dw & 0xffffu)); \
      nd1 = (float)__builtin_bit_cast(_Float16, (unsigned short)(dw >> 16));   \
    } else {                                                                   \
      int jc = j - 1; jc = jc < 0 ? 0 : (jc > 511 ? 511 : jc);                 \
      const float4* py = (const float4*)(ybase + (size_t)jc * 16);             \
      float4 v0 = py[0], v1 = py[1], v2 = py[2], v3 = py[3];                   \
      float yv[16] = { v0.x,v0.y,v0.z,v0.w, v1.x,v1.y,v1.z,v1.w,               \
                       v2.x,v2.y,v2.z,v2.w, v3.x,v3.y,v3.z,v3.w };             \
      float y2 = 0.f, d0 = 0.f, d1 = 0.f;                                      \
      _Pragma("unroll")                                                        \
      for (int q = 0; q < 16; ++q) {                                           \
        y2 = fmaf(yv[q], yv[q], y2);                                           \
        d0 = fmaf(xr0[q], yv[q], d0);                                          \
        d1 = fmaf(xr1[q], yv[q], d1);                                          \
      }                                                                        \
      nd0 = (2.f * d0 - x20 - y2) * INV_LN2;                                   \
      nd1 = (2.f * d1 - x21 - y2) * INV_LN2;                                   \
    }                                                                          \
    /* up = whole-wave shift-up-1 of n1p1 via DPP wf_sr1; lane0 <- ring/BIG */ \
    const int vi = __builtin_bit_cast(int, n1p1);                              \
    const int sh = __builtin_amdgcn_update_dpp(vi, vi, 0x138, 0xF, 0xF, false); \
    float up = __builtin_bit_cast(float, sh);                                  \
    if (l == 0) up = (w == 0) ? BIGV : (RINGV);                                \
    const float dg = upprev;                                                   \
    const float mn0 = fminf(fminf(dg, up), n0p);                               \
    const float s0e = __builtin_amdgcn_exp2f(mn0 - dg)                         \
                    + __builtin_amdgcn_exp2f(mn0 - up)                         \
                    + __builtin_amdgcn_exp2f(mn0 - n0p);                       \
    float c0 = mn0 - __builtin_amdgcn_logf(s0e) - nd0;                         \
    const float mn1 = fminf(fminf(n0p, n1p1), c0);                             \
    const float s1e = __builtin_amdgcn_exp2f(mn1 - n0p)                        \
                    + __builtin_amdgcn_exp2f(mn1 - n1p1)                       \
                    + __builtin_amdgcn_exp2f(mn1 - c0);                        \
    float c1 = mn1 - __builtin_amdgcn_logf(s1e) - nd1;                         \
    const bool valid = (unsigned)(j - 1) < 512u;                               \
    c0 = valid ? c0 : BIGV;                                                    \
    c1 = valid ? c1 : BIGV;                                                    \
    lastv = valid ? c1 : lastv;                                                \
    if (l == 63 && w < 3 && valid) ring[w][(j - 1) & 63] = c1;                 \
    upprev = up; n0p = c0; n1p1 = c1;                                          \
  }

  for (int p = 0; p < 51; ++p) {
    const int pw = p - 5 * w;
    if (pw >= 0 && pw < 36) {
      const int tbase = 16 * pw + 1;
      // per-phase ring prefetch (broadcast; only lane 0 of waves 1-3 uses it)
      const float4* rp = (const float4*)(&ring[w > 0 ? w - 1 : 0][0]);
      const int rb = ((tbase - 1) & 63) >> 2;     // {0,4,8,12}
      float4 rg0 = rp[rb], rg1 = rp[rb + 1], rg2 = rp[rb + 2], rg3 = rp[rb + 3];
      { const int t = tbase + 0;  SDTW_STEP(ds0, rg0.x) }
      { const int t = tbase + 1;  SDTW_STEP(ds1, rg0.y) }
      { const int t = tbase + 2;  SDTW_STEP(ds2, rg0.z) }
      { const int t = tbase + 3;  SDTW_STEP(ds3, rg0.w) }
      { const int t = tbase + 4;  SDTW_STEP(ds0, rg1.x) }
      { const int t = tbase + 5;  SDTW_STEP(ds1, rg1.y) }
      { const int t = tbase + 6;  SDTW_STEP(ds2, rg1.z) }
      { const int t = tbase + 7;  SDTW_STEP(ds3, rg1.w) }
      { const int t = tbase + 8;  SDTW_STEP(ds0, rg2.x) }
      { const int t = tbase + 9;  SDTW_STEP(ds1, rg2.y) }
      { const int t = tbase + 10; SDTW_STEP(ds2, rg2.z) }
      { const int t = tbase + 11; SDTW_STEP(ds3, rg2.w) }
      { const int t = tbase + 12; SDTW_STEP(ds0, rg3.x) }
      { const int t = tbase + 13; SDTW_STEP(ds1, rg3.y) }
      { const int t = tbase + 14; SDTW_STEP(ds2, rg3.z) }
      { const int t = tbase + 15; SDTW_STEP(ds3, rg3.w) }
    }
    __syncthreads();
  }
#undef SDTW_STEP

  if (tid == 255) out[b] = lastv * LN2f;
}

extern "C" void kernel_launch(void* const* d_in, const int* in_sizes, int n_in,
                              void* d_out, int out_size, void* d_ws, size_t ws_size,
                              hipStream_t stream)
{
  const float* x = (const float*)d_in[0];
  const float* y = (const float*)d_in[1];
  float* o = (float*)d_out;
  const size_t need = (size_t)64 * 512 * 512 * 2;
  if (ws_size >= need) {
    _Float16* nd = (_Float16*)d_ws;
    dist_kernel<<<dim3(64, 64), 256, 0, stream>>>(x, y, nd);
    dp_kernel<true><<<64, 256, 0, stream>>>(nd, x, y, o);
  } else {
    dp_kernel<false><<<64, 256, 0, stream>>>(nullptr, x, y, o);
  }
}